// Round 3
// baseline (697.413 us; speedup 1.0000x reference)
//
#include <hip/hip_runtime.h>
#include <cstdint>
#include <cstddef>

#define B_   32
#define WN   64
#define NT   50
#define C_   384
#define NH   12
#define HD   32
#define SCALE 0.17677669529663687f  // 32^-0.5

typedef float  f32x4  __attribute__((ext_vector_type(4)));
typedef __bf16 bf16x8 __attribute__((ext_vector_type(8)));

__device__ __forceinline__ float bf2f(unsigned short u) {
  union { unsigned int u; float f; } v; v.u = ((unsigned int)u) << 16; return v.f;
}
__device__ __forceinline__ unsigned short f2bf(float f) {
  union { float f; unsigned int u; } v; v.f = f;
  unsigned int r = v.u + 0x7FFFu + ((v.u >> 16) & 1u);  // RNE
  return (unsigned short)(r >> 16);
}

__device__ __forceinline__ void gload_lds16(const void* g, void* l) {
  __builtin_amdgcn_global_load_lds(
      (const __attribute__((address_space(1))) void*)g,
      (__attribute__((address_space(3))) void*)l, 16, 0, 0);
}

// ---------------- fp32 -> bf16 conversion ----------------
__global__ __launch_bounds__(256) void cvt_bf16_k(const float* __restrict__ src,
                                                  unsigned short* __restrict__ dst,
                                                  int nquad) {
  int i = blockIdx.x * 256 + threadIdx.x;
  if (i < nquad) {
    float4 v = ((const float4*)src)[i];
    ushort4 o;
    o.x = f2bf(v.x); o.y = f2bf(v.y); o.z = f2bf(v.z); o.w = f2bf(v.w);
    ((ushort4*)dst)[i] = o;
  }
}

// ---- 128x128 MFMA GEMM, 2-phase software pipeline (T3-minimum, m230-V0 recipe) ----
// Out[M][N] = A[M][K] @ W[N][K]^T (+bias).
// Double-buffered LDS; STAGE(tile t+1) issued BEFORE compute(tile t); one raw
// s_barrier per K-step preceded by inline-asm vmcnt(0) (drain overlapped with
// MFMA instead of serialized). XCD-aware bijective swizzle (nwg % 8 == 0).
template<bool OUT_BF16, bool HAS_BIAS>
__global__ __launch_bounds__(256) void gemm128_k(
    const unsigned short* __restrict__ A,
    const unsigned short* __restrict__ W,
    const float* __restrict__ bias,
    void* __restrict__ Out, int M, int N, int K)
{
  __shared__ unsigned short As[2][128 * 32];  // 16 KB
  __shared__ unsigned short Bs[2][128 * 32];  // 16 KB  (32 KB total)
  const int linear = blockIdx.y * gridDim.x + blockIdx.x;
  const int nwg    = gridDim.x * gridDim.y;
  const int chunk  = nwg >> 3;                       // nwg % 8 == 0 by launch contract
  const int wg     = (linear & 7) * chunk + (linear >> 3);
  const int n0 = (wg % gridDim.x) * 128;
  const int m0 = (wg / gridDim.x) * 128;
  const int t  = threadIdx.x;
  const int lane = t & 63, wv = t >> 6;
  const int ln = lane & 15, kq = (lane >> 4) << 3;
  const int wm = (wv >> 1) << 6, wn = (wv & 1) << 6;

  const int row1 = t >> 2;            // 0..63
  const int ce1  = (t & 3) << 3;      // k-element 0/8/16/24
  const int stoff = row1 * 32 + ce1;  // per-thread LDS slot (wave-uniform base + lane*16)
  const size_t arow_a = (size_t)(m0 + row1) * K + ce1;
  const size_t arow_b = (size_t)(n0 + row1) * K + ce1;

  f32x4 acc[4][4];
#pragma unroll
  for (int i = 0; i < 4; ++i)
#pragma unroll
    for (int j = 0; j < 4; ++j) acc[i][j] = (f32x4){0.f, 0.f, 0.f, 0.f};

  const int nkb = K >> 5;

  // prologue: stage tile 0 into buffer 0
  {
    gload_lds16(A + arow_a,                  As[0] + stoff);
    gload_lds16(A + arow_a + (size_t)64 * K, As[0] + stoff + 64 * 32);
    gload_lds16(W + arow_b,                  Bs[0] + stoff);
    gload_lds16(W + arow_b + (size_t)64 * K, Bs[0] + stoff + 64 * 32);
  }
  asm volatile("s_waitcnt vmcnt(0)" ::: "memory");
  __builtin_amdgcn_s_barrier();

  int cur = 0;
  for (int kb = 0; kb < nkb - 1; ++kb) {
    const int k1 = (kb + 1) << 5;
    // issue next tile's loads into the other buffer (overlaps with compute below)
    gload_lds16(A + arow_a + k1,                  As[cur ^ 1] + stoff);
    gload_lds16(A + arow_a + (size_t)64 * K + k1, As[cur ^ 1] + stoff + 64 * 32);
    gload_lds16(W + arow_b + k1,                  Bs[cur ^ 1] + stoff);
    gload_lds16(W + arow_b + (size_t)64 * K + k1, Bs[cur ^ 1] + stoff + 64 * 32);

    // compute current tile
    bf16x8 af[4], bf[4];
#pragma unroll
    for (int i = 0; i < 4; ++i) af[i] = *(const bf16x8*)&As[cur][(wm + i * 16 + ln) * 32 + kq];
#pragma unroll
    for (int j = 0; j < 4; ++j) bf[j] = *(const bf16x8*)&Bs[cur][(wn + j * 16 + ln) * 32 + kq];
#pragma unroll
    for (int i = 0; i < 4; ++i)
#pragma unroll
      for (int j = 0; j < 4; ++j)
        acc[i][j] = __builtin_amdgcn_mfma_f32_16x16x32_bf16(af[i], bf[j], acc[i][j], 0, 0, 0);

    // next tile's LDS writes complete; all waves done reading buf[cur]
    asm volatile("s_waitcnt vmcnt(0)" ::: "memory");
    __builtin_amdgcn_s_barrier();
    cur ^= 1;
  }

  // epilogue tile (already staged + drained)
  {
    bf16x8 af[4], bf[4];
#pragma unroll
    for (int i = 0; i < 4; ++i) af[i] = *(const bf16x8*)&As[cur][(wm + i * 16 + ln) * 32 + kq];
#pragma unroll
    for (int j = 0; j < 4; ++j) bf[j] = *(const bf16x8*)&Bs[cur][(wn + j * 16 + ln) * 32 + kq];
#pragma unroll
    for (int i = 0; i < 4; ++i)
#pragma unroll
      for (int j = 0; j < 4; ++j)
        acc[i][j] = __builtin_amdgcn_mfma_f32_16x16x32_bf16(af[i], bf[j], acc[i][j], 0, 0, 0);
  }

  const int orow = (lane >> 4) << 2;
#pragma unroll
  for (int i = 0; i < 4; ++i)
#pragma unroll
    for (int j = 0; j < 4; ++j) {
      int gn = n0 + wn + j * 16 + ln;
      float bb = HAS_BIAS ? bias[gn] : 0.f;
#pragma unroll
      for (int r = 0; r < 4; ++r) {
        int gm = m0 + wm + i * 16 + orow + r;
        float v = acc[i][j][r] + bb;
        if (OUT_BF16) ((unsigned short*)Out)[(size_t)gm * N + gn] = f2bf(v);
        else          ((float*)Out)[(size_t)gm * N + gn] = v;
      }
    }
}

// ---- 64x64 MFMA GEMM (kept for the small pqk GEMM) ----
template<bool OUT_BF16, bool HAS_BIAS>
__global__ __launch_bounds__(256) void gemm_bf16_k(
    const unsigned short* __restrict__ A,
    const unsigned short* __restrict__ W,
    const float* __restrict__ bias,
    void* __restrict__ Out, int M, int N, int K)
{
  __shared__ unsigned short As[64][40];
  __shared__ unsigned short Bs[64][40];
  const int n0 = blockIdx.x * 64;
  const int m0 = blockIdx.y * 64;
  const int t  = threadIdx.x;
  const int srow = t >> 2;
  const int sseg = (t & 3) << 3;
  const int lane = t & 63;
  const int wv = t >> 6;
  const int wm = (wv >> 1) << 5;
  const int wn = (wv & 1) << 5;
  const int lr = lane & 15;
  const int kq = (lane >> 4) << 3;

  f32x4 acc[2][2] = {{{0.f,0.f,0.f,0.f},{0.f,0.f,0.f,0.f}},
                     {{0.f,0.f,0.f,0.f},{0.f,0.f,0.f,0.f}}};

  const int nkb = K >> 5;
  for (int kb = 0; kb < nkb; ++kb) {
    const int k0 = kb << 5;
    *(uint4*)&As[srow][sseg] = *(const uint4*)(A + (size_t)(m0 + srow) * K + k0 + sseg);
    *(uint4*)&Bs[srow][sseg] = *(const uint4*)(W + (size_t)(n0 + srow) * K + k0 + sseg);
    __syncthreads();
    bf16x8 a0 = *(const bf16x8*)&As[wm + lr][kq];
    bf16x8 a1 = *(const bf16x8*)&As[wm + 16 + lr][kq];
    bf16x8 b0 = *(const bf16x8*)&Bs[wn + lr][kq];
    bf16x8 b1 = *(const bf16x8*)&Bs[wn + 16 + lr][kq];
    acc[0][0] = __builtin_amdgcn_mfma_f32_16x16x32_bf16(a0, b0, acc[0][0], 0, 0, 0);
    acc[0][1] = __builtin_amdgcn_mfma_f32_16x16x32_bf16(a0, b1, acc[0][1], 0, 0, 0);
    acc[1][0] = __builtin_amdgcn_mfma_f32_16x16x32_bf16(a1, b0, acc[1][0], 0, 0, 0);
    acc[1][1] = __builtin_amdgcn_mfma_f32_16x16x32_bf16(a1, b1, acc[1][1], 0, 0, 0);
    __syncthreads();
  }
  const int orow = (lane >> 4) << 2;
#pragma unroll
  for (int i = 0; i < 2; ++i)
#pragma unroll
    for (int j = 0; j < 2; ++j)
#pragma unroll
      for (int r = 0; r < 4; ++r) {
        int gm = m0 + wm + i * 16 + orow + r;
        int gn = n0 + wn + j * 16 + lr;
        float v = acc[i][j][r];
        if (HAS_BIAS) v += bias[gn];
        if (OUT_BF16) ((unsigned short*)Out)[(size_t)gm * N + gn] = f2bf(v);
        else          ((float*)Out)[(size_t)gm * N + gn] = v;
      }
}

// ---- window attention (MFMA): one block per window, all 12 heads ----
__global__ __launch_bounds__(256) void attn_win_k(
    const unsigned short* __restrict__ qkv,
    const unsigned short* __restrict__ xb,
    unsigned short* __restrict__ outA)
{
  const int w = blockIdx.x, b = blockIdx.y;
  const int t = threadIdx.x;
  const int lane = t & 63, wv = t >> 6;
  const int ln = lane & 15, hi = lane >> 4;

  __shared__ unsigned short Qs[64][40];
  __shared__ unsigned short Ks[64][40];
  __shared__ unsigned short Vt[32][72];
  __shared__ unsigned short Ps[64][72];

  const size_t win = (size_t)(b * WN + w);
  const size_t qkvbase = win * NT * 1152;
  const size_t obase = win * NT * C_;

  for (int h = 0; h < NH; ++h) {
    __syncthreads();
    {
      const int n = t >> 2, seg = (t & 3) << 3;
      uint4 qv = {0,0,0,0}, kv = {0,0,0,0}, vv = {0,0,0,0};
      if (n < NT) {
        const unsigned short* p = qkv + qkvbase + (size_t)n * 1152 + h * HD + seg;
        qv = *(const uint4*)p;
        kv = *(const uint4*)(p + C_);
        vv = *(const uint4*)(p + 2 * C_);
      }
      *(uint4*)&Qs[n][seg] = qv;
      *(uint4*)&Ks[n][seg] = kv;
      const unsigned short* vs = (const unsigned short*)&vv;
#pragma unroll
      for (int j = 0; j < 8; ++j) Vt[seg + j][n] = vs[j];
    }
    __syncthreads();

    f32x4 s[4];
    {
      bf16x8 aq = *(const bf16x8*)&Qs[wv * 16 + ln][hi * 8];
#pragma unroll
      for (int nt = 0; nt < 4; ++nt) {
        bf16x8 bk = *(const bf16x8*)&Ks[nt * 16 + ln][hi * 8];
        s[nt] = __builtin_amdgcn_mfma_f32_16x16x32_bf16(aq, bk, (f32x4){0.f,0.f,0.f,0.f}, 0, 0, 0);
      }
    }

#pragma unroll
    for (int r = 0; r < 4; ++r) {
      float m = -1e30f;
#pragma unroll
      for (int nt = 0; nt < 4; ++nt) {
        float val = s[nt][r] * SCALE;
        s[nt][r] = val;
        if (nt * 16 + ln < NT) m = fmaxf(m, val);
      }
#pragma unroll
      for (int o = 1; o < 16; o <<= 1) m = fmaxf(m, __shfl_xor(m, o));
      float e[4]; float sum = 0.f;
#pragma unroll
      for (int nt = 0; nt < 4; ++nt) {
        e[nt] = (nt * 16 + ln < NT) ? __expf(s[nt][r] - m) : 0.f;
        sum += e[nt];
      }
#pragma unroll
      for (int o = 1; o < 16; o <<= 1) sum += __shfl_xor(sum, o);
      float inv = 1.f / sum;
      int q = wv * 16 + hi * 4 + r;
#pragma unroll
      for (int nt = 0; nt < 4; ++nt)
        Ps[q][nt * 16 + ln] = f2bf(e[nt] * inv);
    }

    f32x4 o0 = {0.f,0.f,0.f,0.f}, o1 = {0.f,0.f,0.f,0.f};
#pragma unroll
    for (int kb = 0; kb < 2; ++kb) {
      bf16x8 bp  = *(const bf16x8*)&Ps[wv * 16 + ln][kb * 32 + hi * 8];
      bf16x8 av0 = *(const bf16x8*)&Vt[ln][kb * 32 + hi * 8];
      bf16x8 av1 = *(const bf16x8*)&Vt[16 + ln][kb * 32 + hi * 8];
      o0 = __builtin_amdgcn_mfma_f32_16x16x32_bf16(av0, bp, o0, 0, 0, 0);
      o1 = __builtin_amdgcn_mfma_f32_16x16x32_bf16(av1, bp, o1, 0, 0, 0);
    }

    const int q = wv * 16 + ln;
    if (q < NT) {
      const unsigned short* xr = xb + obase + (size_t)q * C_ + h * HD;
      unsigned short* orow = outA + obase + (size_t)q * C_ + h * HD;
      ushort4 x0 = *(const ushort4*)(xr + hi * 4);
      ushort4 x1 = *(const ushort4*)(xr + 16 + hi * 4);
      ushort4 r0, r1;
      r0.x = f2bf(o0[0] + bf2f(x0.x)); r0.y = f2bf(o0[1] + bf2f(x0.y));
      r0.z = f2bf(o0[2] + bf2f(x0.z)); r0.w = f2bf(o0[3] + bf2f(x0.w));
      r1.x = f2bf(o1[0] + bf2f(x1.x)); r1.y = f2bf(o1[1] + bf2f(x1.y));
      r1.z = f2bf(o1[2] + bf2f(x1.z)); r1.w = f2bf(o1[3] + bf2f(x1.w));
      *(ushort4*)(orow + hi * 4) = r0;
      *(ushort4*)(orow + 16 + hi * 4) = r1;
    }
  }
}

// ---- LN + exact GELU on window tokens ----
__global__ __launch_bounds__(64) void ln_gelu_k(
    const unsigned short* __restrict__ outA,
    const float* __restrict__ g, const float* __restrict__ beta,
    unsigned short* __restrict__ wt)
{
  const int row = blockIdx.x;
  const int t = threadIdx.x;
  const size_t base = (size_t)row * NT * C_;
  float v[6];
  float s = 0.f, s2 = 0.f;
#pragma unroll
  for (int i = 0; i < 6; ++i) {
    float xv = bf2f(outA[base + t + i * 64]);
    v[i] = xv; s += xv; s2 += xv * xv;
  }
#pragma unroll
  for (int off = 1; off < 64; off <<= 1) {
    s  += __shfl_xor(s, off);
    s2 += __shfl_xor(s2, off);
  }
  const float mu = s * (1.f / 384.f);
  const float var = s2 * (1.f / 384.f) - mu * mu;
  const float rinv = rsqrtf(var + 1e-5f);
#pragma unroll
  for (int i = 0; i < 6; ++i) {
    int c = t + i * 64;
    float y = (v[i] - mu) * rinv * g[c] + beta[c];
    float ge = 0.5f * y * (1.f + erff(y * 0.70710678118654752f));
    wt[(size_t)row * C_ + c] = f2bf(ge);
  }
}

// ---- cross-window pooling attention: pattn[b,h,w,v] (fp32) ----
__global__ __launch_bounds__(64) void pool_attn_k(
    const float* __restrict__ pqk, float* __restrict__ pattn)
{
  const int h = blockIdx.x;
  const int b = blockIdx.y;
  const int t = threadIdx.x;
  __shared__ float qs[64][32];
  __shared__ float ks[64][32];
  __shared__ float L[64][64];
  for (int idx = t; idx < 64 * 32; idx += 64) {
    int n = idx >> 5, dd = idx & 31;
    int sw = dd ^ (((n >> 3) & 7) << 2);
    size_t base = ((size_t)(b * WN + n)) * (2 * C_) + h * HD + dd;
    qs[n][sw] = pqk[base];
    ks[n][sw] = pqk[base + C_];
  }
  __syncthreads();
  const int ti = t >> 3, tj = t & 7;
  const int i0 = ti << 3, j0 = tj << 3;
  const int swi = ti << 2, swj = tj << 2;
  {
    float acc[8][8];
#pragma unroll
    for (int r = 0; r < 8; ++r)
#pragma unroll
      for (int c = 0; c < 8; ++c) acc[r][c] = 0.f;
#pragma unroll
    for (int d0 = 0; d0 < 32; d0 += 4) {
      float4 qv[8], kv[8];
#pragma unroll
      for (int r = 0; r < 8; ++r) qv[r] = *(const float4*)&qs[i0 + r][d0 ^ swi];
#pragma unroll
      for (int c = 0; c < 8; ++c) kv[c] = *(const float4*)&ks[j0 + c][d0 ^ swj];
#pragma unroll
      for (int r = 0; r < 8; ++r)
#pragma unroll
        for (int c = 0; c < 8; ++c)
          acc[r][c] += qv[r].x * kv[c].x + qv[r].y * kv[c].y + qv[r].z * kv[c].z + qv[r].w * kv[c].w;
    }
#pragma unroll
    for (int r = 0; r < 8; ++r)
#pragma unroll
      for (int c4 = 0; c4 < 2; ++c4) {
        float4 o;
        o.x = acc[r][c4 * 4 + 0] * SCALE; o.y = acc[r][c4 * 4 + 1] * SCALE;
        o.z = acc[r][c4 * 4 + 2] * SCALE; o.w = acc[r][c4 * 4 + 3] * SCALE;
        *(float4*)&L[i0 + r][(j0 + c4 * 4) ^ swi] = o;
      }
  }
  __syncthreads();
  {
    const int sw = (t >> 3) << 2;
    float m = -1e30f;
    for (int j = 0; j < 64; ++j) m = fmaxf(m, L[t][j ^ sw]);
    float sum = 0.f;
    for (int j = 0; j < 64; ++j) { float e = __expf(L[t][j ^ sw] - m); L[t][j ^ sw] = e; sum += e; }
    float inv = 1.f / sum;
    float* dst = pattn + (((size_t)b * NH + h) * 64 + t) * 64;
    for (int j = 0; j < 64; ++j) dst[j] = L[t][j ^ sw] * inv;
  }
}

// ---- pooled SA via MFMA: psa = pattn @ ax, + ax residual, rearrange, bf16 Y ----
__global__ __launch_bounds__(256) void pool_sa_mfma_k(
    const float* __restrict__ pattn,
    const unsigned short* __restrict__ outA,
    unsigned short* __restrict__ Y)
{
  const int tt = blockIdx.x;   // s-tile 0..6 == image sub-row srow
  const int h  = blockIdx.y;
  const int b  = blockIdx.z;
  const int t  = threadIdx.x;

  __shared__ unsigned short Ph[64][72];
  __shared__ unsigned short Pl[64][72];
  __shared__ unsigned short AXT[224][72];

  // ---- stage P (fp32 -> bf16 hi/lo split) ----
  {
    const float4* src = (const float4*)(pattn + ((size_t)b * NH + h) * 4096);
#pragma unroll
    for (int i = 0; i < 4; ++i) {
      int idx = t + i * 256;
      int row = idx >> 4, seg = (idx & 15) << 2;
      float4 p = src[idx];
      float pv[4] = {p.x, p.y, p.z, p.w};
      unsigned short hs[4], ls[4];
#pragma unroll
      for (int e = 0; e < 4; ++e) {
        hs[e] = f2bf(pv[e]);
        ls[e] = f2bf(pv[e] - bf2f(hs[e]));
      }
      ushort4 hv, lv;
      hv.x = hs[0]; hv.y = hs[1]; hv.z = hs[2]; hv.w = hs[3];
      lv.x = ls[0]; lv.y = ls[1]; lv.z = ls[2]; lv.w = ls[3];
      *(ushort4*)&Ph[row][seg] = hv;
      *(ushort4*)&Pl[row][seg] = lv;
    }
  }

  // ---- stage ax tile transposed: AXT[sd][v], chunk-rotated ----
  {
    const unsigned short* axb = outA + ((size_t)(b * WN) * NT + 1 + tt * 7) * C_ + h * HD;
    for (int idx = t; idx < 896; idx += 256) {
      int v2 = idx / 28;
      int c  = idx - v2 * 28;
      int v  = v2 << 1;
      int s  = c >> 2, d8 = (c & 3) << 3;
      const unsigned short* p0 = axb + (size_t)v * (NT * C_) + s * C_ + d8;
      uint4 a0 = *(const uint4*)p0;
      uint4 a1 = *(const uint4*)(p0 + NT * C_);
      int cp = ((v2 >> 2) + (c & 7)) & 7;
      int bo = cp * 8 + (v2 & 3) * 2;
      unsigned int aw[4] = {a0.x, a0.y, a0.z, a0.w};
      unsigned int bw[4] = {a1.x, a1.y, a1.z, a1.w};
      int r0 = c << 3;
#pragma unroll
      for (int jj = 0; jj < 4; ++jj) {
        unsigned int w0 = (aw[jj] & 0xffffu) | (bw[jj] << 16);
        unsigned int w1 = (aw[jj] >> 16) | (bw[jj] & 0xffff0000u);
        *(unsigned int*)&AXT[r0 + jj * 2    ][bo] = w0;
        *(unsigned int*)&AXT[r0 + jj * 2 + 1][bo] = w1;
      }
    }
  }
  __syncthreads();

  const int lane = t & 63, wv = t >> 6;
  const int ln = lane & 15, hi = lane >> 4;

  bf16x8 afh[2], afl[2];
#pragma unroll
  for (int kb = 0; kb < 2; ++kb) {
    afh[kb] = *(const bf16x8*)&Ph[wv * 16 + ln][kb * 32 + hi * 8];
    afl[kb] = *(const bf16x8*)&Pl[wv * 16 + ln][kb * 32 + hi * 8];
  }

  const int wbase  = wv * 16 + hi * 4;
  const int whi    = wbase >> 3;
  const int wlo    = wbase & 7;
  const int wchunk = wbase >> 3;
  unsigned short* yb = Y + ((size_t)b * 3136 + ((size_t)whi * 7 + tt) * 56) * C_ + h * HD;

#pragma unroll
  for (int j = 0; j < 14; ++j) {
    const int row = j * 16 + ln;
    const int g = (row >> 3) & 7;
    f32x4 acc = {0.f, 0.f, 0.f, 0.f};
#pragma unroll
    for (int kb = 0; kb < 2; ++kb) {
      bf16x8 bfr = *(const bf16x8*)&AXT[row][((kb * 4 + hi + g) & 7) * 8];
      acc = __builtin_amdgcn_mfma_f32_16x16x32_bf16(afh[kb], bfr, acc, 0, 0, 0);
      acc = __builtin_amdgcn_mfma_f32_16x16x32_bf16(afl[kb], bfr, acc, 0, 0, 0);
    }
    ushort4 rx = *(const ushort4*)&AXT[row][((wchunk + g) & 7) * 8 + (wbase & 7)];
    const unsigned short rr[4] = {rx.x, rx.y, rx.z, rx.w};
    const int sl = row >> 5, d = row & 31;
    unsigned short* yp = yb + (size_t)(wlo * 7 + sl) * C_ + d;
#pragma unroll
    for (int r = 0; r < 4; ++r)
      yp[(size_t)r * 7 * C_] = f2bf(acc[r] + bf2f(rr[r]));
  }
}

extern "C" void kernel_launch(void* const* d_in, const int* in_sizes, int n_in,
                              void* d_out, int out_size, void* d_ws, size_t ws_size,
                              hipStream_t stream)
{
  (void)in_sizes; (void)n_in; (void)out_size; (void)ws_size;
  const float* x      = (const float*)d_in[0];
  const float* w_qkv  = (const float*)d_in[3];
  const float* w_qk   = (const float*)d_in[4];
  const float* ln_g   = (const float*)d_in[5];
  const float* ln_b   = (const float*)d_in[6];
  const float* w_proj = (const float*)d_in[7];
  const float* b_proj = (const float*)d_in[8];
  float* out = (float*)d_out;

  char* ws = (char*)d_ws;
  size_t off = 0;
  auto alloc = [&](size_t bytes) { size_t o = off; off += (bytes + 255) & ~(size_t)255; return o; };
  const size_t M1 = (size_t)B_ * WN * NT;   // 102400
  const size_t M7 = (size_t)B_ * 3136;      // 100352
  unsigned short* qkv    = (unsigned short*)(ws + alloc(M1 * 1152 * 2));
  unsigned short* xb     = (unsigned short*)(ws + alloc(M1 * C_ * 2));
  unsigned short* outA   = (unsigned short*)(ws + alloc(M1 * C_ * 2));
  unsigned short* wqkvb  = (unsigned short*)(ws + alloc(1152 * 384 * 2));
  unsigned short* wqkb   = (unsigned short*)(ws + alloc(768 * 384 * 2));
  unsigned short* wprojb = (unsigned short*)(ws + alloc(384 * 384 * 2));
  unsigned short* wt     = (unsigned short*)(ws + alloc(2048 * 384 * 2));
  float* pqk             = (float*)(ws + alloc(2048 * 768 * 4));
  float* pattn           = (float*)(ws + alloc((size_t)B_ * NH * 64 * 64 * 4));
  unsigned short* Y = xb;  // xb dead after attn_win_k, overwritten by pool_sa

  int q;
  q = (int)(M1 * C_ / 4);
  cvt_bf16_k<<<(q + 255) / 256, 256, 0, stream>>>(x, xb, q);
  q = 1152 * 384 / 4;
  cvt_bf16_k<<<(q + 255) / 256, 256, 0, stream>>>(w_qkv, wqkvb, q);
  q = 768 * 384 / 4;
  cvt_bf16_k<<<(q + 255) / 256, 256, 0, stream>>>(w_qk, wqkb, q);
  q = 384 * 384 / 4;
  cvt_bf16_k<<<(q + 255) / 256, 256, 0, stream>>>(w_proj, wprojb, q);

  // 1) qkv = x @ w_qkv^T  (bf16 out) — pipelined + XCD-swizzled (7200 blocks)
  gemm128_k<true, false><<<dim3(1152 / 128, M1 / 128), 256, 0, stream>>>(
      xb, wqkvb, nullptr, qkv, (int)M1, 1152, 384);
  // 2) window attention + residual
  attn_win_k<<<dim3(WN, B_), 256, 0, stream>>>(qkv, xb, outA);
  // 3) LN + exact GELU on window tokens
  ln_gelu_k<<<2048, 64, 0, stream>>>(outA, ln_g, ln_b, wt);
  // 4) pqk = wt @ w_qk^T (fp32 out)
  gemm_bf16_k<false, false><<<dim3(768 / 64, 2048 / 64), 256, 0, stream>>>(
      wt, wqkb, nullptr, pqk, 2048, 768, 384);
  // 5) cross-window softmax attention
  pool_attn_k<<<dim3(NH, B_), 64, 0, stream>>>(pqk, pattn);
  // 6) psa + ax residual + window->image rearrange (MFMA, bf16 Y)
  pool_sa_mfma_k<<<dim3(7, NH, B_), 256, 0, stream>>>(pattn, outA, Y);
  // 7) out = Y @ w_proj^T + b_proj (fp32) — pipelined + XCD-swizzled (2352 blocks)
  gemm128_k<false, true><<<dim3(384 / 128, M7 / 128), 256, 0, stream>>>(
      Y, wprojb, b_proj, out, (int)M7, 384, 384);
}

// Round 4
// 690.178 us; speedup vs baseline: 1.0105x; 1.0105x over previous
//
#include <hip/hip_runtime.h>
#include <cstdint>
#include <cstddef>

#define B_   32
#define WN   64
#define NT   50
#define C_   384
#define NH   12
#define HD   32
#define SCALE 0.17677669529663687f  // 32^-0.5

typedef float  f32x4  __attribute__((ext_vector_type(4)));
typedef __bf16 bf16x8 __attribute__((ext_vector_type(8)));

__device__ __forceinline__ float bf2f(unsigned short u) {
  union { unsigned int u; float f; } v; v.u = ((unsigned int)u) << 16; return v.f;
}
__device__ __forceinline__ unsigned short f2bf(float f) {
  union { float f; unsigned int u; } v; v.f = f;
  unsigned int r = v.u + 0x7FFFu + ((v.u >> 16) & 1u);  // RNE
  return (unsigned short)(r >> 16);
}

__device__ __forceinline__ void gload_lds16(const void* g, void* l) {
  __builtin_amdgcn_global_load_lds(
      (const __attribute__((address_space(1))) void*)g,
      (__attribute__((address_space(3))) void*)l, 16, 0, 0);
}

// ---------------- fp32 -> bf16 conversion ----------------
__global__ __launch_bounds__(256) void cvt_bf16_k(const float* __restrict__ src,
                                                  unsigned short* __restrict__ dst,
                                                  int nquad) {
  int i = blockIdx.x * 256 + threadIdx.x;
  if (i < nquad) {
    float4 v = ((const float4*)src)[i];
    ushort4 o;
    o.x = f2bf(v.x); o.y = f2bf(v.y); o.z = f2bf(v.z); o.w = f2bf(v.w);
    ((ushort4*)dst)[i] = o;
  }
}

// ---- 128x128 MFMA GEMM, counted-vmcnt pipeline (T4, m218 mechanism) ----
// Out[M][N] = A[M][K] @ W[N][K]^T (+bias).  Requires K/32 >= 2.
// Ledger (per wave; 4 loads per tile-stage):
//   prologue: stage k0, k1      -> in-flight 8;  vmcnt(4) => k0 ready; barrier
//   iter kb : ds_read buf[kb&1]; lgkmcnt(0); barrier   (all waves done reading)
//             stage k(kb+2) into buf[kb&1]             (in-flight: k(kb+1),k(kb+2))
//             16 MFMA
//             vmcnt(4) => k(kb+1) ready (4 newest stay in flight across barrier)
//             barrier
//   tail    : kb+2>=nkb -> no stage; vmcnt(0) before last-compute barrier.
// XCD-aware bijective swizzle (nwg % 8 == 0 by launch contract).
template<bool OUT_BF16, bool HAS_BIAS>
__global__ __launch_bounds__(256) void gemm128_k(
    const unsigned short* __restrict__ A,
    const unsigned short* __restrict__ W,
    const float* __restrict__ bias,
    void* __restrict__ Out, int M, int N, int K)
{
  __shared__ unsigned short As[2][128 * 32];  // 16 KB
  __shared__ unsigned short Bs[2][128 * 32];  // 16 KB  (32 KB total)
  const int linear = blockIdx.y * gridDim.x + blockIdx.x;
  const int nwg    = gridDim.x * gridDim.y;
  const int chunk  = nwg >> 3;
  const int wg     = (linear & 7) * chunk + (linear >> 3);
  const int n0 = (wg % gridDim.x) * 128;
  const int m0 = (wg / gridDim.x) * 128;
  const int t  = threadIdx.x;
  const int lane = t & 63, wv = t >> 6;
  const int ln = lane & 15, kq = (lane >> 4) << 3;
  const int wm = (wv >> 1) << 6, wn = (wv & 1) << 6;

  const int row1 = t >> 2;            // 0..63
  const int ce1  = (t & 3) << 3;      // k-element 0/8/16/24
  const int stoff = row1 * 32 + ce1;  // lane-linear LDS slot (DMA constraint)
  const unsigned short* gA = A + (size_t)(m0 + row1) * K + ce1;
  const unsigned short* gB = W + (size_t)(n0 + row1) * K + ce1;
  const size_t hstep = (size_t)64 * K;

  f32x4 acc[4][4];
#pragma unroll
  for (int i = 0; i < 4; ++i)
#pragma unroll
    for (int j = 0; j < 4; ++j) acc[i][j] = (f32x4){0.f, 0.f, 0.f, 0.f};

  const int nkb = K >> 5;   // >= 2 by contract

  // prologue: stage tiles 0 and 1
  gload_lds16(gA,              As[0] + stoff);
  gload_lds16(gA + hstep,      As[0] + stoff + 64 * 32);
  gload_lds16(gB,              Bs[0] + stoff);
  gload_lds16(gB + hstep,      Bs[0] + stoff + 64 * 32);
  gload_lds16(gA + 32,         As[1] + stoff);
  gload_lds16(gA + hstep + 32, As[1] + stoff + 64 * 32);
  gload_lds16(gB + 32,         Bs[1] + stoff);
  gload_lds16(gB + hstep + 32, Bs[1] + stoff + 64 * 32);
  asm volatile("s_waitcnt vmcnt(4)" ::: "memory");   // tile 0 landed
  __builtin_amdgcn_s_barrier();

  for (int kb = 0; kb < nkb; ++kb) {
    const int cur = kb & 1;
    bf16x8 af[4], bf[4];
#pragma unroll
    for (int i = 0; i < 4; ++i) af[i] = *(const bf16x8*)&As[cur][(wm + i * 16 + ln) * 32 + kq];
#pragma unroll
    for (int j = 0; j < 4; ++j) bf[j] = *(const bf16x8*)&Bs[cur][(wn + j * 16 + ln) * 32 + kq];
    asm volatile("s_waitcnt lgkmcnt(0)" ::: "memory");  // this wave's reads landed
    __builtin_amdgcn_s_barrier();                       // ALL waves done reading buf[cur]

    if (kb + 2 < nkb) {                                 // stage tile kb+2 over buf[cur]
      const int ko = (kb + 2) << 5;
      gload_lds16(gA + ko,         As[cur] + stoff);
      gload_lds16(gA + hstep + ko, As[cur] + stoff + 64 * 32);
      gload_lds16(gB + ko,         Bs[cur] + stoff);
      gload_lds16(gB + hstep + ko, Bs[cur] + stoff + 64 * 32);
    }

#pragma unroll
    for (int i = 0; i < 4; ++i)
#pragma unroll
      for (int j = 0; j < 4; ++j)
        acc[i][j] = __builtin_amdgcn_mfma_f32_16x16x32_bf16(af[i], bf[j], acc[i][j], 0, 0, 0);

    if (kb + 1 < nkb) {
      if (kb + 2 < nkb) asm volatile("s_waitcnt vmcnt(4)" ::: "memory"); // next tile ready, newest 4 fly on
      else              asm volatile("s_waitcnt vmcnt(0)" ::: "memory"); // tail: nothing newer in flight
      __builtin_amdgcn_s_barrier();
    }
  }

  const int orow = (lane >> 4) << 2;
#pragma unroll
  for (int i = 0; i < 4; ++i)
#pragma unroll
    for (int j = 0; j < 4; ++j) {
      int gn = n0 + wn + j * 16 + ln;
      float bb = HAS_BIAS ? bias[gn] : 0.f;
#pragma unroll
      for (int r = 0; r < 4; ++r) {
        int gm = m0 + wm + i * 16 + orow + r;
        float v = acc[i][j][r] + bb;
        if (OUT_BF16) ((unsigned short*)Out)[(size_t)gm * N + gn] = f2bf(v);
        else          ((float*)Out)[(size_t)gm * N + gn] = v;
      }
    }
}

// ---- 64x64 MFMA GEMM (kept for the small pqk GEMM) ----
template<bool OUT_BF16, bool HAS_BIAS>
__global__ __launch_bounds__(256) void gemm_bf16_k(
    const unsigned short* __restrict__ A,
    const unsigned short* __restrict__ W,
    const float* __restrict__ bias,
    void* __restrict__ Out, int M, int N, int K)
{
  __shared__ unsigned short As[64][40];
  __shared__ unsigned short Bs[64][40];
  const int n0 = blockIdx.x * 64;
  const int m0 = blockIdx.y * 64;
  const int t  = threadIdx.x;
  const int srow = t >> 2;
  const int sseg = (t & 3) << 3;
  const int lane = t & 63;
  const int wv = t >> 6;
  const int wm = (wv >> 1) << 5;
  const int wn = (wv & 1) << 5;
  const int lr = lane & 15;
  const int kq = (lane >> 4) << 3;

  f32x4 acc[2][2] = {{{0.f,0.f,0.f,0.f},{0.f,0.f,0.f,0.f}},
                     {{0.f,0.f,0.f,0.f},{0.f,0.f,0.f,0.f}}};

  const int nkb = K >> 5;
  for (int kb = 0; kb < nkb; ++kb) {
    const int k0 = kb << 5;
    *(uint4*)&As[srow][sseg] = *(const uint4*)(A + (size_t)(m0 + srow) * K + k0 + sseg);
    *(uint4*)&Bs[srow][sseg] = *(const uint4*)(W + (size_t)(n0 + srow) * K + k0 + sseg);
    __syncthreads();
    bf16x8 a0 = *(const bf16x8*)&As[wm + lr][kq];
    bf16x8 a1 = *(const bf16x8*)&As[wm + 16 + lr][kq];
    bf16x8 b0 = *(const bf16x8*)&Bs[wn + lr][kq];
    bf16x8 b1 = *(const bf16x8*)&Bs[wn + 16 + lr][kq];
    acc[0][0] = __builtin_amdgcn_mfma_f32_16x16x32_bf16(a0, b0, acc[0][0], 0, 0, 0);
    acc[0][1] = __builtin_amdgcn_mfma_f32_16x16x32_bf16(a0, b1, acc[0][1], 0, 0, 0);
    acc[1][0] = __builtin_amdgcn_mfma_f32_16x16x32_bf16(a1, b0, acc[1][0], 0, 0, 0);
    acc[1][1] = __builtin_amdgcn_mfma_f32_16x16x32_bf16(a1, b1, acc[1][1], 0, 0, 0);
    __syncthreads();
  }
  const int orow = (lane >> 4) << 2;
#pragma unroll
  for (int i = 0; i < 2; ++i)
#pragma unroll
    for (int j = 0; j < 2; ++j)
#pragma unroll
      for (int r = 0; r < 4; ++r) {
        int gm = m0 + wm + i * 16 + orow + r;
        int gn = n0 + wn + j * 16 + lr;
        float v = acc[i][j][r];
        if (HAS_BIAS) v += bias[gn];
        if (OUT_BF16) ((unsigned short*)Out)[(size_t)gm * N + gn] = f2bf(v);
        else          ((float*)Out)[(size_t)gm * N + gn] = v;
      }
}

// ---- window attention (MFMA): one block per window, all 12 heads ----
__global__ __launch_bounds__(256) void attn_win_k(
    const unsigned short* __restrict__ qkv,
    const unsigned short* __restrict__ xb,
    unsigned short* __restrict__ outA)
{
  const int w = blockIdx.x, b = blockIdx.y;
  const int t = threadIdx.x;
  const int lane = t & 63, wv = t >> 6;
  const int ln = lane & 15, hi = lane >> 4;

  __shared__ unsigned short Qs[64][40];
  __shared__ unsigned short Ks[64][40];
  __shared__ unsigned short Vt[32][72];
  __shared__ unsigned short Ps[64][72];

  const size_t win = (size_t)(b * WN + w);
  const size_t qkvbase = win * NT * 1152;
  const size_t obase = win * NT * C_;

  for (int h = 0; h < NH; ++h) {
    __syncthreads();
    {
      const int n = t >> 2, seg = (t & 3) << 3;
      uint4 qv = {0,0,0,0}, kv = {0,0,0,0}, vv = {0,0,0,0};
      if (n < NT) {
        const unsigned short* p = qkv + qkvbase + (size_t)n * 1152 + h * HD + seg;
        qv = *(const uint4*)p;
        kv = *(const uint4*)(p + C_);
        vv = *(const uint4*)(p + 2 * C_);
      }
      *(uint4*)&Qs[n][seg] = qv;
      *(uint4*)&Ks[n][seg] = kv;
      const unsigned short* vs = (const unsigned short*)&vv;
#pragma unroll
      for (int j = 0; j < 8; ++j) Vt[seg + j][n] = vs[j];
    }
    __syncthreads();

    f32x4 s[4];
    {
      bf16x8 aq = *(const bf16x8*)&Qs[wv * 16 + ln][hi * 8];
#pragma unroll
      for (int nt = 0; nt < 4; ++nt) {
        bf16x8 bk = *(const bf16x8*)&Ks[nt * 16 + ln][hi * 8];
        s[nt] = __builtin_amdgcn_mfma_f32_16x16x32_bf16(aq, bk, (f32x4){0.f,0.f,0.f,0.f}, 0, 0, 0);
      }
    }

#pragma unroll
    for (int r = 0; r < 4; ++r) {
      float m = -1e30f;
#pragma unroll
      for (int nt = 0; nt < 4; ++nt) {
        float val = s[nt][r] * SCALE;
        s[nt][r] = val;
        if (nt * 16 + ln < NT) m = fmaxf(m, val);
      }
#pragma unroll
      for (int o = 1; o < 16; o <<= 1) m = fmaxf(m, __shfl_xor(m, o));
      float e[4]; float sum = 0.f;
#pragma unroll
      for (int nt = 0; nt < 4; ++nt) {
        e[nt] = (nt * 16 + ln < NT) ? __expf(s[nt][r] - m) : 0.f;
        sum += e[nt];
      }
#pragma unroll
      for (int o = 1; o < 16; o <<= 1) sum += __shfl_xor(sum, o);
      float inv = 1.f / sum;
      int q = wv * 16 + hi * 4 + r;
#pragma unroll
      for (int nt = 0; nt < 4; ++nt)
        Ps[q][nt * 16 + ln] = f2bf(e[nt] * inv);
    }

    f32x4 o0 = {0.f,0.f,0.f,0.f}, o1 = {0.f,0.f,0.f,0.f};
#pragma unroll
    for (int kb = 0; kb < 2; ++kb) {
      bf16x8 bp  = *(const bf16x8*)&Ps[wv * 16 + ln][kb * 32 + hi * 8];
      bf16x8 av0 = *(const bf16x8*)&Vt[ln][kb * 32 + hi * 8];
      bf16x8 av1 = *(const bf16x8*)&Vt[16 + ln][kb * 32 + hi * 8];
      o0 = __builtin_amdgcn_mfma_f32_16x16x32_bf16(av0, bp, o0, 0, 0, 0);
      o1 = __builtin_amdgcn_mfma_f32_16x16x32_bf16(av1, bp, o1, 0, 0, 0);
    }

    const int q = wv * 16 + ln;
    if (q < NT) {
      const unsigned short* xr = xb + obase + (size_t)q * C_ + h * HD;
      unsigned short* orow = outA + obase + (size_t)q * C_ + h * HD;
      ushort4 x0 = *(const ushort4*)(xr + hi * 4);
      ushort4 x1 = *(const ushort4*)(xr + 16 + hi * 4);
      ushort4 r0, r1;
      r0.x = f2bf(o0[0] + bf2f(x0.x)); r0.y = f2bf(o0[1] + bf2f(x0.y));
      r0.z = f2bf(o0[2] + bf2f(x0.z)); r0.w = f2bf(o0[3] + bf2f(x0.w));
      r1.x = f2bf(o1[0] + bf2f(x1.x)); r1.y = f2bf(o1[1] + bf2f(x1.y));
      r1.z = f2bf(o1[2] + bf2f(x1.z)); r1.w = f2bf(o1[3] + bf2f(x1.w));
      *(ushort4*)(orow + hi * 4) = r0;
      *(ushort4*)(orow + 16 + hi * 4) = r1;
    }
  }
}

// ---- LN + exact GELU on window tokens ----
__global__ __launch_bounds__(64) void ln_gelu_k(
    const unsigned short* __restrict__ outA,
    const float* __restrict__ g, const float* __restrict__ beta,
    unsigned short* __restrict__ wt)
{
  const int row = blockIdx.x;
  const int t = threadIdx.x;
  const size_t base = (size_t)row * NT * C_;
  float v[6];
  float s = 0.f, s2 = 0.f;
#pragma unroll
  for (int i = 0; i < 6; ++i) {
    float xv = bf2f(outA[base + t + i * 64]);
    v[i] = xv; s += xv; s2 += xv * xv;
  }
#pragma unroll
  for (int off = 1; off < 64; off <<= 1) {
    s  += __shfl_xor(s, off);
    s2 += __shfl_xor(s2, off);
  }
  const float mu = s * (1.f / 384.f);
  const float var = s2 * (1.f / 384.f) - mu * mu;
  const float rinv = rsqrtf(var + 1e-5f);
#pragma unroll
  for (int i = 0; i < 6; ++i) {
    int c = t + i * 64;
    float y = (v[i] - mu) * rinv * g[c] + beta[c];
    float ge = 0.5f * y * (1.f + erff(y * 0.70710678118654752f));
    wt[(size_t)row * C_ + c] = f2bf(ge);
  }
}

// ---- cross-window pooling attention: pattn[b,h,w,v] (fp32) ----
__global__ __launch_bounds__(64) void pool_attn_k(
    const float* __restrict__ pqk, float* __restrict__ pattn)
{
  const int h = blockIdx.x;
  const int b = blockIdx.y;
  const int t = threadIdx.x;
  __shared__ float qs[64][32];
  __shared__ float ks[64][32];
  __shared__ float L[64][64];
  for (int idx = t; idx < 64 * 32; idx += 64) {
    int n = idx >> 5, dd = idx & 31;
    int sw = dd ^ (((n >> 3) & 7) << 2);
    size_t base = ((size_t)(b * WN + n)) * (2 * C_) + h * HD + dd;
    qs[n][sw] = pqk[base];
    ks[n][sw] = pqk[base + C_];
  }
  __syncthreads();
  const int ti = t >> 3, tj = t & 7;
  const int i0 = ti << 3, j0 = tj << 3;
  const int swi = ti << 2, swj = tj << 2;
  {
    float acc[8][8];
#pragma unroll
    for (int r = 0; r < 8; ++r)
#pragma unroll
      for (int c = 0; c < 8; ++c) acc[r][c] = 0.f;
#pragma unroll
    for (int d0 = 0; d0 < 32; d0 += 4) {
      float4 qv[8], kv[8];
#pragma unroll
      for (int r = 0; r < 8; ++r) qv[r] = *(const float4*)&qs[i0 + r][d0 ^ swi];
#pragma unroll
      for (int c = 0; c < 8; ++c) kv[c] = *(const float4*)&ks[j0 + c][d0 ^ swj];
#pragma unroll
      for (int r = 0; r < 8; ++r)
#pragma unroll
        for (int c = 0; c < 8; ++c)
          acc[r][c] += qv[r].x * kv[c].x + qv[r].y * kv[c].y + qv[r].z * kv[c].z + qv[r].w * kv[c].w;
    }
#pragma unroll
    for (int r = 0; r < 8; ++r)
#pragma unroll
      for (int c4 = 0; c4 < 2; ++c4) {
        float4 o;
        o.x = acc[r][c4 * 4 + 0] * SCALE; o.y = acc[r][c4 * 4 + 1] * SCALE;
        o.z = acc[r][c4 * 4 + 2] * SCALE; o.w = acc[r][c4 * 4 + 3] * SCALE;
        *(float4*)&L[i0 + r][(j0 + c4 * 4) ^ swi] = o;
      }
  }
  __syncthreads();
  {
    const int sw = (t >> 3) << 2;
    float m = -1e30f;
    for (int j = 0; j < 64; ++j) m = fmaxf(m, L[t][j ^ sw]);
    float sum = 0.f;
    for (int j = 0; j < 64; ++j) { float e = __expf(L[t][j ^ sw] - m); L[t][j ^ sw] = e; sum += e; }
    float inv = 1.f / sum;
    float* dst = pattn + (((size_t)b * NH + h) * 64 + t) * 64;
    for (int j = 0; j < 64; ++j) dst[j] = L[t][j ^ sw] * inv;
  }
}

// ---- pooled SA via MFMA: psa = pattn @ ax, + ax residual, rearrange, bf16 Y ----
__global__ __launch_bounds__(256) void pool_sa_mfma_k(
    const float* __restrict__ pattn,
    const unsigned short* __restrict__ outA,
    unsigned short* __restrict__ Y)
{
  const int tt = blockIdx.x;   // s-tile 0..6 == image sub-row srow
  const int h  = blockIdx.y;
  const int b  = blockIdx.z;
  const int t  = threadIdx.x;

  __shared__ unsigned short Ph[64][72];
  __shared__ unsigned short Pl[64][72];
  __shared__ unsigned short AXT[224][72];

  // ---- stage P (fp32 -> bf16 hi/lo split) ----
  {
    const float4* src = (const float4*)(pattn + ((size_t)b * NH + h) * 4096);
#pragma unroll
    for (int i = 0; i < 4; ++i) {
      int idx = t + i * 256;
      int row = idx >> 4, seg = (idx & 15) << 2;
      float4 p = src[idx];
      float pv[4] = {p.x, p.y, p.z, p.w};
      unsigned short hs[4], ls[4];
#pragma unroll
      for (int e = 0; e < 4; ++e) {
        hs[e] = f2bf(pv[e]);
        ls[e] = f2bf(pv[e] - bf2f(hs[e]));
      }
      ushort4 hv, lv;
      hv.x = hs[0]; hv.y = hs[1]; hv.z = hs[2]; hv.w = hs[3];
      lv.x = ls[0]; lv.y = ls[1]; lv.z = ls[2]; lv.w = ls[3];
      *(ushort4*)&Ph[row][seg] = hv;
      *(ushort4*)&Pl[row][seg] = lv;
    }
  }

  // ---- stage ax tile transposed: AXT[sd][v], chunk-rotated ----
  {
    const unsigned short* axb = outA + ((size_t)(b * WN) * NT + 1 + tt * 7) * C_ + h * HD;
    for (int idx = t; idx < 896; idx += 256) {
      int v2 = idx / 28;
      int c  = idx - v2 * 28;
      int v  = v2 << 1;
      int s  = c >> 2, d8 = (c & 3) << 3;
      const unsigned short* p0 = axb + (size_t)v * (NT * C_) + s * C_ + d8;
      uint4 a0 = *(const uint4*)p0;
      uint4 a1 = *(const uint4*)(p0 + NT * C_);
      int cp = ((v2 >> 2) + (c & 7)) & 7;
      int bo = cp * 8 + (v2 & 3) * 2;
      unsigned int aw[4] = {a0.x, a0.y, a0.z, a0.w};
      unsigned int bw[4] = {a1.x, a1.y, a1.z, a1.w};
      int r0 = c << 3;
#pragma unroll
      for (int jj = 0; jj < 4; ++jj) {
        unsigned int w0 = (aw[jj] & 0xffffu) | (bw[jj] << 16);
        unsigned int w1 = (aw[jj] >> 16) | (bw[jj] & 0xffff0000u);
        *(unsigned int*)&AXT[r0 + jj * 2    ][bo] = w0;
        *(unsigned int*)&AXT[r0 + jj * 2 + 1][bo] = w1;
      }
    }
  }
  __syncthreads();

  const int lane = t & 63, wv = t >> 6;
  const int ln = lane & 15, hi = lane >> 4;

  bf16x8 afh[2], afl[2];
#pragma unroll
  for (int kb = 0; kb < 2; ++kb) {
    afh[kb] = *(const bf16x8*)&Ph[wv * 16 + ln][kb * 32 + hi * 8];
    afl[kb] = *(const bf16x8*)&Pl[wv * 16 + ln][kb * 32 + hi * 8];
  }

  const int wbase  = wv * 16 + hi * 4;
  const int whi    = wbase >> 3;
  const int wlo    = wbase & 7;
  const int wchunk = wbase >> 3;
  unsigned short* yb = Y + ((size_t)b * 3136 + ((size_t)whi * 7 + tt) * 56) * C_ + h * HD;

#pragma unroll
  for (int j = 0; j < 14; ++j) {
    const int row = j * 16 + ln;
    const int g = (row >> 3) & 7;
    f32x4 acc = {0.f, 0.f, 0.f, 0.f};
#pragma unroll
    for (int kb = 0; kb < 2; ++kb) {
      bf16x8 bfr = *(const bf16x8*)&AXT[row][((kb * 4 + hi + g) & 7) * 8];
      acc = __builtin_amdgcn_mfma_f32_16x16x32_bf16(afh[kb], bfr, acc, 0, 0, 0);
      acc = __builtin_amdgcn_mfma_f32_16x16x32_bf16(afl[kb], bfr, acc, 0, 0, 0);
    }
    ushort4 rx = *(const ushort4*)&AXT[row][((wchunk + g) & 7) * 8 + (wbase & 7)];
    const unsigned short rr[4] = {rx.x, rx.y, rx.z, rx.w};
    const int sl = row >> 5, d = row & 31;
    unsigned short* yp = yb + (size_t)(wlo * 7 + sl) * C_ + d;
#pragma unroll
    for (int r = 0; r < 4; ++r)
      yp[(size_t)r * 7 * C_] = f2bf(acc[r] + bf2f(rr[r]));
  }
}

extern "C" void kernel_launch(void* const* d_in, const int* in_sizes, int n_in,
                              void* d_out, int out_size, void* d_ws, size_t ws_size,
                              hipStream_t stream)
{
  (void)in_sizes; (void)n_in; (void)out_size; (void)ws_size;
  const float* x      = (const float*)d_in[0];
  const float* w_qkv  = (const float*)d_in[3];
  const float* w_qk   = (const float*)d_in[4];
  const float* ln_g   = (const float*)d_in[5];
  const float* ln_b   = (const float*)d_in[6];
  const float* w_proj = (const float*)d_in[7];
  const float* b_proj = (const float*)d_in[8];
  float* out = (float*)d_out;

  char* ws = (char*)d_ws;
  size_t off = 0;
  auto alloc = [&](size_t bytes) { size_t o = off; off += (bytes + 255) & ~(size_t)255; return o; };
  const size_t M1 = (size_t)B_ * WN * NT;   // 102400
  const size_t M7 = (size_t)B_ * 3136;      // 100352
  unsigned short* qkv    = (unsigned short*)(ws + alloc(M1 * 1152 * 2));
  unsigned short* xb     = (unsigned short*)(ws + alloc(M1 * C_ * 2));
  unsigned short* outA   = (unsigned short*)(ws + alloc(M1 * C_ * 2));
  unsigned short* wqkvb  = (unsigned short*)(ws + alloc(1152 * 384 * 2));
  unsigned short* wqkb   = (unsigned short*)(ws + alloc(768 * 384 * 2));
  unsigned short* wprojb = (unsigned short*)(ws + alloc(384 * 384 * 2));
  unsigned short* wt     = (unsigned short*)(ws + alloc(2048 * 384 * 2));
  float* pqk             = (float*)(ws + alloc(2048 * 768 * 4));
  float* pattn           = (float*)(ws + alloc((size_t)B_ * NH * 64 * 64 * 4));
  unsigned short* Y = xb;  // xb dead after attn_win_k, overwritten by pool_sa

  int q;
  q = (int)(M1 * C_ / 4);
  cvt_bf16_k<<<(q + 255) / 256, 256, 0, stream>>>(x, xb, q);
  q = 1152 * 384 / 4;
  cvt_bf16_k<<<(q + 255) / 256, 256, 0, stream>>>(w_qkv, wqkvb, q);
  q = 768 * 384 / 4;
  cvt_bf16_k<<<(q + 255) / 256, 256, 0, stream>>>(w_qk, wqkb, q);
  q = 384 * 384 / 4;
  cvt_bf16_k<<<(q + 255) / 256, 256, 0, stream>>>(w_proj, wprojb, q);

  // 1) qkv = x @ w_qkv^T  (bf16 out) — counted-vmcnt pipeline + XCD swizzle
  gemm128_k<true, false><<<dim3(1152 / 128, M1 / 128), 256, 0, stream>>>(
      xb, wqkvb, nullptr, qkv, (int)M1, 1152, 384);
  // 2) window attention + residual
  attn_win_k<<<dim3(WN, B_), 256, 0, stream>>>(qkv, xb, outA);
  // 3) LN + exact GELU on window tokens
  ln_gelu_k<<<2048, 64, 0, stream>>>(outA, ln_g, ln_b, wt);
  // 4) pqk = wt @ w_qk^T (fp32 out)
  gemm_bf16_k<false, false><<<dim3(768 / 64, 2048 / 64), 256, 0, stream>>>(
      wt, wqkb, nullptr, pqk, 2048, 768, 384);
  // 5) cross-window softmax attention
  pool_attn_k<<<dim3(NH, B_), 64, 0, stream>>>(pqk, pattn);
  // 6) psa + ax residual + window->image rearrange (MFMA, bf16 Y)
  pool_sa_mfma_k<<<dim3(7, NH, B_), 256, 0, stream>>>(pattn, outA, Y);
  // 7) out = Y @ w_proj^T + b_proj (fp32) — counted-vmcnt pipeline + XCD swizzle
  gemm128_k<false, true><<<dim3(384 / 128, M7 / 128), 256, 0, stream>>>(
      Y, wprojb, b_proj, out, (int)M7, 384, 384);
}

// Round 6
// 683.871 us; speedup vs baseline: 1.0198x; 1.0092x over previous
//
#include <hip/hip_runtime.h>
#include <cstdint>
#include <cstddef>

#define B_   32
#define WN   64
#define NT   50
#define C_   384
#define NH   12
#define HD   32
#define SCALE 0.17677669529663687f  // 32^-0.5

typedef float  f32x4  __attribute__((ext_vector_type(4)));
typedef __bf16 bf16x8 __attribute__((ext_vector_type(8)));

__device__ __forceinline__ float bf2f(unsigned short u) {
  union { unsigned int u; float f; } v; v.u = ((unsigned int)u) << 16; return v.f;
}
__device__ __forceinline__ unsigned short f2bf(float f) {
  union { float f; unsigned int u; } v; v.f = f;
  unsigned int r = v.u + 0x7FFFu + ((v.u >> 16) & 1u);  // RNE
  return (unsigned short)(r >> 16);
}

__device__ __forceinline__ void gload_lds16(const void* g, void* l) {
  __builtin_amdgcn_global_load_lds(
      (const __attribute__((address_space(1))) void*)g,
      (__attribute__((address_space(3))) void*)l, 16, 0, 0);
}

// ---------------- fp32 -> bf16 conversion ----------------
__global__ __launch_bounds__(256) void cvt_bf16_k(const float* __restrict__ src,
                                                  unsigned short* __restrict__ dst,
                                                  int nquad) {
  int i = blockIdx.x * 256 + threadIdx.x;
  if (i < nquad) {
    float4 v = ((const float4*)src)[i];
    ushort4 o;
    o.x = f2bf(v.x); o.y = f2bf(v.y); o.z = f2bf(v.z); o.w = f2bf(v.w);
    ((ushort4*)dst)[i] = o;
  }
}

// ---- 256x128 MFMA GEMM, 128x64 wave-tiles + counted-vmcnt pipeline ----
// Out[M][N] = A[M][K] @ W[N][K]^T (+bias).  M%256==0, N%128==0, K/32>=2.
// Mechanism: LDS-read-bound fix. 64x64 wave-tile = 512 B LDS per MFMA (m97
// structure ceiling ~31% MfmaUtil); 128x64 wave-tile = 384 B/MFMA and 2x the
// MFMA work per resident wave -> ceiling ~41%.
// 4 waves (2M x 2N), acc 8x4 frags (~176 VGPR) -> __launch_bounds__(256,2).
// Counted-vmcnt ledger (6 loads per tile-stage):
//   prologue: stage k0,k1 (12 in flight); vmcnt(6) => k0 ready; barrier
//   iter kb : ds_read buf[kb&1] (12 b128); lgkmcnt(0); barrier;
//             stage k(kb+2) over buf[kb&1]; 32 MFMA;
//             vmcnt(6) => k(kb+1) ready, k(kb+2)'s 6 fly on; barrier
//   tail    : no stage; vmcnt(0) before last-compute barrier.
// XCD-aware bijective swizzle (nwg % 8 == 0 by launch contract).
template<bool OUT_BF16, bool HAS_BIAS>
__global__ __launch_bounds__(256, 2) void gemm256_k(
    const unsigned short* __restrict__ A,
    const unsigned short* __restrict__ W,
    const float* __restrict__ bias,
    void* __restrict__ Out, int M, int N, int K)
{
  __shared__ unsigned short As[2][256 * 32];  // 16 KB x2
  __shared__ unsigned short Bs[2][128 * 32];  //  8 KB x2  (48 KB total)
  const int linear = blockIdx.y * gridDim.x + blockIdx.x;
  const int nwg    = gridDim.x * gridDim.y;
  const int chunk  = nwg >> 3;
  const int wg     = (linear & 7) * chunk + (linear >> 3);
  const int n0 = (wg % gridDim.x) * 128;
  const int m0 = (wg / gridDim.x) * 256;
  const int t  = threadIdx.x;
  const int lane = t & 63, wv = t >> 6;
  const int ln = lane & 15, kq = (lane >> 4) << 3;
  const int wm = (wv >> 1) << 7;   // 0 or 128
  const int wn = (wv & 1) << 6;    // 0 or 64

  const int rowt = t >> 2;            // 0..63
  const int ce1  = (t & 3) << 3;      // k-element 0/8/16/24
  const int stoff = rowt * 32 + ce1;  // lane-linear LDS slot (DMA constraint)
  const unsigned short* gA = A + (size_t)(m0 + rowt) * K + ce1;
  const unsigned short* gB = W + (size_t)(n0 + rowt) * K + ce1;
  const size_t astep = (size_t)64 * K;

  f32x4 acc[8][4];
#pragma unroll
  for (int i = 0; i < 8; ++i)
#pragma unroll
    for (int j = 0; j < 4; ++j) acc[i][j] = (f32x4){0.f, 0.f, 0.f, 0.f};

  const int nkb = K >> 5;   // >= 2 by contract

#define STAGE_TILE(kb_, buf_)                                              \
  do {                                                                     \
    const int ko_ = (kb_) << 5;                                            \
    gload_lds16(gA + ko_,             As[buf_] + stoff);                   \
    gload_lds16(gA + astep + ko_,     As[buf_] + stoff + 64 * 32);         \
    gload_lds16(gA + 2 * astep + ko_, As[buf_] + stoff + 128 * 32);        \
    gload_lds16(gA + 3 * astep + ko_, As[buf_] + stoff + 192 * 32);        \
    gload_lds16(gB + ko_,             Bs[buf_] + stoff);                   \
    gload_lds16(gB + astep + ko_,     Bs[buf_] + stoff + 64 * 32);         \
  } while (0)

  STAGE_TILE(0, 0);
  STAGE_TILE(1, 1);
  asm volatile("s_waitcnt vmcnt(6)" ::: "memory");   // tile 0 landed
  __builtin_amdgcn_s_barrier();

  for (int kb = 0; kb < nkb; ++kb) {
    const int cur = kb & 1;
    bf16x8 af[8], bf[4];
#pragma unroll
    for (int i = 0; i < 8; ++i) af[i] = *(const bf16x8*)&As[cur][(wm + i * 16 + ln) * 32 + kq];
#pragma unroll
    for (int j = 0; j < 4; ++j) bf[j] = *(const bf16x8*)&Bs[cur][(wn + j * 16 + ln) * 32 + kq];
    asm volatile("s_waitcnt lgkmcnt(0)" ::: "memory");  // this wave's reads landed
    __builtin_amdgcn_s_barrier();                       // ALL waves done reading buf[cur]

    if (kb + 2 < nkb) STAGE_TILE(kb + 2, cur);

    __builtin_amdgcn_s_setprio(1);
#pragma unroll
    for (int i = 0; i < 8; ++i)
#pragma unroll
      for (int j = 0; j < 4; ++j)
        acc[i][j] = __builtin_amdgcn_mfma_f32_16x16x32_bf16(af[i], bf[j], acc[i][j], 0, 0, 0);
    __builtin_amdgcn_s_setprio(0);

    if (kb + 1 < nkb) {
      if (kb + 2 < nkb) asm volatile("s_waitcnt vmcnt(6)" ::: "memory"); // next tile ready
      else              asm volatile("s_waitcnt vmcnt(0)" ::: "memory"); // tail drain
      __builtin_amdgcn_s_barrier();
    }
  }
#undef STAGE_TILE

  const int orow = (lane >> 4) << 2;
#pragma unroll
  for (int i = 0; i < 8; ++i)
#pragma unroll
    for (int j = 0; j < 4; ++j) {
      int gn = n0 + wn + j * 16 + ln;
      float bb = HAS_BIAS ? bias[gn] : 0.f;
#pragma unroll
      for (int r = 0; r < 4; ++r) {
        int gm = m0 + wm + i * 16 + orow + r;
        float v = acc[i][j][r] + bb;
        if (OUT_BF16) ((unsigned short*)Out)[(size_t)gm * N + gn] = f2bf(v);
        else          ((float*)Out)[(size_t)gm * N + gn] = v;
      }
    }
}

// ---- 64x64 MFMA GEMM (kept for the small pqk GEMM) ----
template<bool OUT_BF16, bool HAS_BIAS>
__global__ __launch_bounds__(256) void gemm_bf16_k(
    const unsigned short* __restrict__ A,
    const unsigned short* __restrict__ W,
    const float* __restrict__ bias,
    void* __restrict__ Out, int M, int N, int K)
{
  __shared__ unsigned short As[64][40];
  __shared__ unsigned short Bs[64][40];
  const int n0 = blockIdx.x * 64;
  const int m0 = blockIdx.y * 64;
  const int t  = threadIdx.x;
  const int srow = t >> 2;
  const int sseg = (t & 3) << 3;
  const int lane = t & 63;
  const int wv = t >> 6;
  const int wm = (wv >> 1) << 5;
  const int wn = (wv & 1) << 5;
  const int lr = lane & 15;
  const int kq = (lane >> 4) << 3;

  f32x4 acc[2][2] = {{{0.f,0.f,0.f,0.f},{0.f,0.f,0.f,0.f}},
                     {{0.f,0.f,0.f,0.f},{0.f,0.f,0.f,0.f}}};

  const int nkb = K >> 5;
  for (int kb = 0; kb < nkb; ++kb) {
    const int k0 = kb << 5;
    *(uint4*)&As[srow][sseg] = *(const uint4*)(A + (size_t)(m0 + srow) * K + k0 + sseg);
    *(uint4*)&Bs[srow][sseg] = *(const uint4*)(W + (size_t)(n0 + srow) * K + k0 + sseg);
    __syncthreads();
    bf16x8 a0 = *(const bf16x8*)&As[wm + lr][kq];
    bf16x8 a1 = *(const bf16x8*)&As[wm + 16 + lr][kq];
    bf16x8 b0 = *(const bf16x8*)&Bs[wn + lr][kq];
    bf16x8 b1 = *(const bf16x8*)&Bs[wn + 16 + lr][kq];
    acc[0][0] = __builtin_amdgcn_mfma_f32_16x16x32_bf16(a0, b0, acc[0][0], 0, 0, 0);
    acc[0][1] = __builtin_amdgcn_mfma_f32_16x16x32_bf16(a0, b1, acc[0][1], 0, 0, 0);
    acc[1][0] = __builtin_amdgcn_mfma_f32_16x16x32_bf16(a1, b0, acc[1][0], 0, 0, 0);
    acc[1][1] = __builtin_amdgcn_mfma_f32_16x16x32_bf16(a1, b1, acc[1][1], 0, 0, 0);
    __syncthreads();
  }
  const int orow = (lane >> 4) << 2;
#pragma unroll
  for (int i = 0; i < 2; ++i)
#pragma unroll
    for (int j = 0; j < 2; ++j)
#pragma unroll
      for (int r = 0; r < 4; ++r) {
        int gm = m0 + wm + i * 16 + orow + r;
        int gn = n0 + wn + j * 16 + lr;
        float v = acc[i][j][r];
        if (HAS_BIAS) v += bias[gn];
        if (OUT_BF16) ((unsigned short*)Out)[(size_t)gm * N + gn] = f2bf(v);
        else          ((float*)Out)[(size_t)gm * N + gn] = v;
      }
}

// ---- window attention (MFMA): one block per window, all 12 heads ----
__global__ __launch_bounds__(256) void attn_win_k(
    const unsigned short* __restrict__ qkv,
    const unsigned short* __restrict__ xb,
    unsigned short* __restrict__ outA)
{
  const int w = blockIdx.x, b = blockIdx.y;
  const int t = threadIdx.x;
  const int lane = t & 63, wv = t >> 6;
  const int ln = lane & 15, hi = lane >> 4;

  __shared__ unsigned short Qs[64][40];
  __shared__ unsigned short Ks[64][40];
  __shared__ unsigned short Vt[32][72];
  __shared__ unsigned short Ps[64][72];

  const size_t win = (size_t)(b * WN + w);
  const size_t qkvbase = win * NT * 1152;
  const size_t obase = win * NT * C_;

  for (int h = 0; h < NH; ++h) {
    __syncthreads();
    {
      const int n = t >> 2, seg = (t & 3) << 3;
      uint4 qv = {0,0,0,0}, kv = {0,0,0,0}, vv = {0,0,0,0};
      if (n < NT) {
        const unsigned short* p = qkv + qkvbase + (size_t)n * 1152 + h * HD + seg;
        qv = *(const uint4*)p;
        kv = *(const uint4*)(p + C_);
        vv = *(const uint4*)(p + 2 * C_);
      }
      *(uint4*)&Qs[n][seg] = qv;
      *(uint4*)&Ks[n][seg] = kv;
      const unsigned short* vs = (const unsigned short*)&vv;
#pragma unroll
      for (int j = 0; j < 8; ++j) Vt[seg + j][n] = vs[j];
    }
    __syncthreads();

    f32x4 s[4];
    {
      bf16x8 aq = *(const bf16x8*)&Qs[wv * 16 + ln][hi * 8];
#pragma unroll
      for (int nt = 0; nt < 4; ++nt) {
        bf16x8 bk = *(const bf16x8*)&Ks[nt * 16 + ln][hi * 8];
        s[nt] = __builtin_amdgcn_mfma_f32_16x16x32_bf16(aq, bk, (f32x4){0.f,0.f,0.f,0.f}, 0, 0, 0);
      }
    }

#pragma unroll
    for (int r = 0; r < 4; ++r) {
      float m = -1e30f;
#pragma unroll
      for (int nt = 0; nt < 4; ++nt) {
        float val = s[nt][r] * SCALE;
        s[nt][r] = val;
        if (nt * 16 + ln < NT) m = fmaxf(m, val);
      }
#pragma unroll
      for (int o = 1; o < 16; o <<= 1) m = fmaxf(m, __shfl_xor(m, o));
      float e[4]; float sum = 0.f;
#pragma unroll
      for (int nt = 0; nt < 4; ++nt) {
        e[nt] = (nt * 16 + ln < NT) ? __expf(s[nt][r] - m) : 0.f;
        sum += e[nt];
      }
#pragma unroll
      for (int o = 1; o < 16; o <<= 1) sum += __shfl_xor(sum, o);
      float inv = 1.f / sum;
      int q = wv * 16 + hi * 4 + r;
#pragma unroll
      for (int nt = 0; nt < 4; ++nt)
        Ps[q][nt * 16 + ln] = f2bf(e[nt] * inv);
    }

    f32x4 o0 = {0.f,0.f,0.f,0.f}, o1 = {0.f,0.f,0.f,0.f};
#pragma unroll
    for (int kb = 0; kb < 2; ++kb) {
      bf16x8 bp  = *(const bf16x8*)&Ps[wv * 16 + ln][kb * 32 + hi * 8];
      bf16x8 av0 = *(const bf16x8*)&Vt[ln][kb * 32 + hi * 8];
      bf16x8 av1 = *(const bf16x8*)&Vt[16 + ln][kb * 32 + hi * 8];
      o0 = __builtin_amdgcn_mfma_f32_16x16x32_bf16(av0, bp, o0, 0, 0, 0);
      o1 = __builtin_amdgcn_mfma_f32_16x16x32_bf16(av1, bp, o1, 0, 0, 0);
    }

    const int q = wv * 16 + ln;
    if (q < NT) {
      const unsigned short* xr = xb + obase + (size_t)q * C_ + h * HD;
      unsigned short* orow = outA + obase + (size_t)q * C_ + h * HD;
      ushort4 x0 = *(const ushort4*)(xr + hi * 4);
      ushort4 x1 = *(const ushort4*)(xr + 16 + hi * 4);
      ushort4 r0, r1;
      r0.x = f2bf(o0[0] + bf2f(x0.x)); r0.y = f2bf(o0[1] + bf2f(x0.y));
      r0.z = f2bf(o0[2] + bf2f(x0.z)); r0.w = f2bf(o0[3] + bf2f(x0.w));
      r1.x = f2bf(o1[0] + bf2f(x1.x)); r1.y = f2bf(o1[1] + bf2f(x1.y));
      r1.z = f2bf(o1[2] + bf2f(x1.z)); r1.w = f2bf(o1[3] + bf2f(x1.w));
      *(ushort4*)(orow + hi * 4) = r0;
      *(ushort4*)(orow + 16 + hi * 4) = r1;
    }
  }
}

// ---- LN + exact GELU on window tokens ----
__global__ __launch_bounds__(64) void ln_gelu_k(
    const unsigned short* __restrict__ outA,
    const float* __restrict__ g, const float* __restrict__ beta,
    unsigned short* __restrict__ wt)
{
  const int row = blockIdx.x;
  const int t = threadIdx.x;
  const size_t base = (size_t)row * NT * C_;
  float v[6];
  float s = 0.f, s2 = 0.f;
#pragma unroll
  for (int i = 0; i < 6; ++i) {
    float xv = bf2f(outA[base + t + i * 64]);
    v[i] = xv; s += xv; s2 += xv * xv;
  }
#pragma unroll
  for (int off = 1; off < 64; off <<= 1) {
    s  += __shfl_xor(s, off);
    s2 += __shfl_xor(s2, off);
  }
  const float mu = s * (1.f / 384.f);
  const float var = s2 * (1.f / 384.f) - mu * mu;
  const float rinv = rsqrtf(var + 1e-5f);
#pragma unroll
  for (int i = 0; i < 6; ++i) {
    int c = t + i * 64;
    float y = (v[i] - mu) * rinv * g[c] + beta[c];
    float ge = 0.5f * y * (1.f + erff(y * 0.70710678118654752f));
    wt[(size_t)row * C_ + c] = f2bf(ge);
  }
}

// ---- cross-window pooling attention: pattn[b,h,w,v] (fp32) ----
__global__ __launch_bounds__(64) void pool_attn_k(
    const float* __restrict__ pqk, float* __restrict__ pattn)
{
  const int h = blockIdx.x;
  const int b = blockIdx.y;
  const int t = threadIdx.x;
  __shared__ float qs[64][32];
  __shared__ float ks[64][32];
  __shared__ float L[64][64];
  for (int idx = t; idx < 64 * 32; idx += 64) {
    int n = idx >> 5, dd = idx & 31;
    int sw = dd ^ (((n >> 3) & 7) << 2);
    size_t base = ((size_t)(b * WN + n)) * (2 * C_) + h * HD + dd;
    qs[n][sw] = pqk[base];
    ks[n][sw] = pqk[base + C_];
  }
  __syncthreads();
  const int ti = t >> 3, tj = t & 7;
  const int i0 = ti << 3, j0 = tj << 3;
  const int swi = ti << 2, swj = tj << 2;
  {
    float acc[8][8];
#pragma unroll
    for (int r = 0; r < 8; ++r)
#pragma unroll
      for (int c = 0; c < 8; ++c) acc[r][c] = 0.f;
#pragma unroll
    for (int d0 = 0; d0 < 32; d0 += 4) {
      float4 qv[8], kv[8];
#pragma unroll
      for (int r = 0; r < 8; ++r) qv[r] = *(const float4*)&qs[i0 + r][d0 ^ swi];
#pragma unroll
      for (int c = 0; c < 8; ++c) kv[c] = *(const float4*)&ks[j0 + c][d0 ^ swj];
#pragma unroll
      for (int r = 0; r < 8; ++r)
#pragma unroll
        for (int c = 0; c < 8; ++c)
          acc[r][c] += qv[r].x * kv[c].x + qv[r].y * kv[c].y + qv[r].z * kv[c].z + qv[r].w * kv[c].w;
    }
#pragma unroll
    for (int r = 0; r < 8; ++r)
#pragma unroll
      for (int c4 = 0; c4 < 2; ++c4) {
        float4 o;
        o.x = acc[r][c4 * 4 + 0] * SCALE; o.y = acc[r][c4 * 4 + 1] * SCALE;
        o.z = acc[r][c4 * 4 + 2] * SCALE; o.w = acc[r][c4 * 4 + 3] * SCALE;
        *(float4*)&L[i0 + r][(j0 + c4 * 4) ^ swi] = o;
      }
  }
  __syncthreads();
  {
    const int sw = (t >> 3) << 2;
    float m = -1e30f;
    for (int j = 0; j < 64; ++j) m = fmaxf(m, L[t][j ^ sw]);
    float sum = 0.f;
    for (int j = 0; j < 64; ++j) { float e = __expf(L[t][j ^ sw] - m); L[t][j ^ sw] = e; sum += e; }
    float inv = 1.f / sum;
    float* dst = pattn + (((size_t)b * NH + h) * 64 + t) * 64;
    for (int j = 0; j < 64; ++j) dst[j] = L[t][j ^ sw] * inv;
  }
}

// ---- pooled SA via MFMA: psa = pattn @ ax, + ax residual, rearrange, bf16 Y ----
__global__ __launch_bounds__(256) void pool_sa_mfma_k(
    const float* __restrict__ pattn,
    const unsigned short* __restrict__ outA,
    unsigned short* __restrict__ Y)
{
  const int tt = blockIdx.x;   // s-tile 0..6 == image sub-row srow
  const int h  = blockIdx.y;
  const int b  = blockIdx.z;
  const int t  = threadIdx.x;

  __shared__ unsigned short Ph[64][72];
  __shared__ unsigned short Pl[64][72];
  __shared__ unsigned short AXT[224][72];

  // ---- stage P (fp32 -> bf16 hi/lo split) ----
  {
    const float4* src = (const float4*)(pattn + ((size_t)b * NH + h) * 4096);
#pragma unroll
    for (int i = 0; i < 4; ++i) {
      int idx = t + i * 256;
      int row = idx >> 4, seg = (idx & 15) << 2;
      float4 p = src[idx];
      float pv[4] = {p.x, p.y, p.z, p.w};
      unsigned short hs[4], ls[4];
#pragma unroll
      for (int e = 0; e < 4; ++e) {
        hs[e] = f2bf(pv[e]);
        ls[e] = f2bf(pv[e] - bf2f(hs[e]));
      }
      ushort4 hv, lv;
      hv.x = hs[0]; hv.y = hs[1]; hv.z = hs[2]; hv.w = hs[3];
      lv.x = ls[0]; lv.y = ls[1]; lv.z = ls[2]; lv.w = ls[3];
      *(ushort4*)&Ph[row][seg] = hv;
      *(ushort4*)&Pl[row][seg] = lv;
    }
  }

  // ---- stage ax tile transposed: AXT[sd][v], chunk-rotated ----
  {
    const unsigned short* axb = outA + ((size_t)(b * WN) * NT + 1 + tt * 7) * C_ + h * HD;
    for (int idx = t; idx < 896; idx += 256) {
      int v2 = idx / 28;
      int c  = idx - v2 * 28;
      int v  = v2 << 1;
      int s  = c >> 2, d8 = (c & 3) << 3;
      const unsigned short* p0 = axb + (size_t)v * (NT * C_) + s * C_ + d8;
      uint4 a0 = *(const uint4*)p0;
      uint4 a1 = *(const uint4*)(p0 + NT * C_);
      int cp = ((v2 >> 2) + (c & 7)) & 7;
      int bo = cp * 8 + (v2 & 3) * 2;
      unsigned int aw[4] = {a0.x, a0.y, a0.z, a0.w};
      unsigned int bw[4] = {a1.x, a1.y, a1.z, a1.w};
      int r0 = c << 3;
#pragma unroll
      for (int jj = 0; jj < 4; ++jj) {
        unsigned int w0 = (aw[jj] & 0xffffu) | (bw[jj] << 16);
        unsigned int w1 = (aw[jj] >> 16) | (bw[jj] & 0xffff0000u);
        *(unsigned int*)&AXT[r0 + jj * 2    ][bo] = w0;
        *(unsigned int*)&AXT[r0 + jj * 2 + 1][bo] = w1;
      }
    }
  }
  __syncthreads();

  const int lane = t & 63, wv = t >> 6;
  const int ln = lane & 15, hi = lane >> 4;

  bf16x8 afh[2], afl[2];
#pragma unroll
  for (int kb = 0; kb < 2; ++kb) {
    afh[kb] = *(const bf16x8*)&Ph[wv * 16 + ln][kb * 32 + hi * 8];
    afl[kb] = *(const bf16x8*)&Pl[wv * 16 + ln][kb * 32 + hi * 8];
  }

  const int wbase  = wv * 16 + hi * 4;
  const int whi    = wbase >> 3;
  const int wlo    = wbase & 7;
  const int wchunk = wbase >> 3;
  unsigned short* yb = Y + ((size_t)b * 3136 + ((size_t)whi * 7 + tt) * 56) * C_ + h * HD;

#pragma unroll
  for (int j = 0; j < 14; ++j) {
    const int row = j * 16 + ln;
    const int g = (row >> 3) & 7;
    f32x4 acc = {0.f, 0.f, 0.f, 0.f};
#pragma unroll
    for (int kb = 0; kb < 2; ++kb) {
      bf16x8 bfr = *(const bf16x8*)&AXT[row][((kb * 4 + hi + g) & 7) * 8];
      acc = __builtin_amdgcn_mfma_f32_16x16x32_bf16(afh[kb], bfr, acc, 0, 0, 0);
      acc = __builtin_amdgcn_mfma_f32_16x16x32_bf16(afl[kb], bfr, acc, 0, 0, 0);
    }
    ushort4 rx = *(const ushort4*)&AXT[row][((wchunk + g) & 7) * 8 + (wbase & 7)];
    const unsigned short rr[4] = {rx.x, rx.y, rx.z, rx.w};
    const int sl = row >> 5, d = row & 31;
    unsigned short* yp = yb + (size_t)(wlo * 7 + sl) * C_ + d;
#pragma unroll
    for (int r = 0; r < 4; ++r)
      yp[(size_t)r * 7 * C_] = f2bf(acc[r] + bf2f(rr[r]));
  }
}

extern "C" void kernel_launch(void* const* d_in, const int* in_sizes, int n_in,
                              void* d_out, int out_size, void* d_ws, size_t ws_size,
                              hipStream_t stream)
{
  (void)in_sizes; (void)n_in; (void)out_size; (void)ws_size;
  const float* x      = (const float*)d_in[0];
  const float* w_qkv  = (const float*)d_in[3];
  const float* w_qk   = (const float*)d_in[4];
  const float* ln_g   = (const float*)d_in[5];
  const float* ln_b   = (const float*)d_in[6];
  const float* w_proj = (const float*)d_in[7];
  const float* b_proj = (const float*)d_in[8];
  float* out = (float*)d_out;

  char* ws = (char*)d_ws;
  size_t off = 0;
  auto alloc = [&](size_t bytes) { size_t o = off; off += (bytes + 255) & ~(size_t)255; return o; };
  const size_t M1 = (size_t)B_ * WN * NT;   // 102400
  const size_t M7 = (size_t)B_ * 3136;      // 100352
  unsigned short* qkv    = (unsigned short*)(ws + alloc(M1 * 1152 * 2));
  unsigned short* xb     = (unsigned short*)(ws + alloc(M1 * C_ * 2));
  unsigned short* outA   = (unsigned short*)(ws + alloc(M1 * C_ * 2));
  unsigned short* wqkvb  = (unsigned short*)(ws + alloc(1152 * 384 * 2));
  unsigned short* wqkb   = (unsigned short*)(ws + alloc(768 * 384 * 2));
  unsigned short* wprojb = (unsigned short*)(ws + alloc(384 * 384 * 2));
  unsigned short* wt     = (unsigned short*)(ws + alloc(2048 * 384 * 2));
  float* pqk             = (float*)(ws + alloc(2048 * 768 * 4));
  float* pattn           = (float*)(ws + alloc((size_t)B_ * NH * 64 * 64 * 4));
  unsigned short* Y = xb;  // xb dead after attn_win_k, overwritten by pool_sa

  int q;
  q = (int)(M1 * C_ / 4);
  cvt_bf16_k<<<(q + 255) / 256, 256, 0, stream>>>(x, xb, q);
  q = 1152 * 384 / 4;
  cvt_bf16_k<<<(q + 255) / 256, 256, 0, stream>>>(w_qkv, wqkvb, q);
  q = 768 * 384 / 4;
  cvt_bf16_k<<<(q + 255) / 256, 256, 0, stream>>>(w_qk, wqkb, q);
  q = 384 * 384 / 4;
  cvt_bf16_k<<<(q + 255) / 256, 256, 0, stream>>>(w_proj, wprojb, q);

  // 1) qkv = x @ w_qkv^T  (bf16 out) — 256x128 tile, 128x64 wave-tiles
  //    grid 9 x 400 = 3600 blocks (%8==0)
  gemm256_k<true, false><<<dim3(1152 / 128, M1 / 256), 256, 0, stream>>>(
      xb, wqkvb, nullptr, qkv, (int)M1, 1152, 384);
  // 2) window attention + residual
  attn_win_k<<<dim3(WN, B_), 256, 0, stream>>>(qkv, xb, outA);
  // 3) LN + exact GELU on window tokens
  ln_gelu_k<<<2048, 64, 0, stream>>>(outA, ln_g, ln_b, wt);
  // 4) pqk = wt @ w_qk^T (fp32 out)
  gemm_bf16_k<false, false><<<dim3(768 / 64, 2048 / 64), 256, 0, stream>>>(
      wt, wqkb, nullptr, pqk, 2048, 768, 384);
  // 5) cross-window softmax attention
  pool_attn_k<<<dim3(NH, B_), 64, 0, stream>>>(pqk, pattn);
  // 6) psa + ax residual + window->image rearrange (MFMA, bf16 Y)
  pool_sa_mfma_k<<<dim3(7, NH, B_), 256, 0, stream>>>(pattn, outA, Y);
  // 7) out = Y @ w_proj^T + b_proj (fp32) — grid 3 x 392 = 1176 blocks (%8==0)
  gemm256_k<false, true><<<dim3(384 / 128, M7 / 256), 256, 0, stream>>>(
      Y, wprojb, b_proj, out, (int)M7, 384, 384);
}